// Round 5
// baseline (102.899 us; speedup 1.0000x reference)
//
#include <hip/hip_runtime.h>
#include <hip/hip_bf16.h>

typedef __attribute__((ext_vector_type(8))) short short8;
typedef __attribute__((ext_vector_type(4))) float float4v;

#define N_ROWS 4096
#define K_DIM  192
#define NT     32                       // 128-tiles per dim
#define NSYM   528                      // 32*33/2 upper-tri blocks
#define NBLK   2080                     // 2*528 + 1024
#define REG_A0 0
#define REG_B0 24576
#define REG_S1 49152                    // stage-1 region base (A at +0, B at +24576)
#define LDS_TOTAL (98304 + 32)
#define C1     (-0.72134752044448179f)  // -0.5*log2(e)
#define LOG2E  (1.4426950408889634f)

typedef const __attribute__((address_space(1))) unsigned int* gp_t;
typedef __attribute__((address_space(3))) unsigned int* lp_t;

__device__ __forceinline__ void gload16(const void* g, char* l) {
    // async global->LDS DMA: 16B/lane, dest = wave-uniform base + lane*16
    __builtin_amdgcn_global_load_lds((gp_t)g, (lp_t)l, 16, 0, 0);
}

// ---- kernel 1: fp32 -> bf16 convert + per-row sum of squares (of bf16 values) ----
__global__ void prep_kernel(const float* __restrict__ x, const float* __restrict__ y,
                            __hip_bfloat16* __restrict__ xb, __hip_bfloat16* __restrict__ yb,
                            float* __restrict__ sqx, float* __restrict__ sqy)
{
    int w    = (blockIdx.x * blockDim.x + threadIdx.x) >> 6;  // one row per wave
    int lane = threadIdx.x & 63;
    if (w >= 2 * N_ROWS) return;
    const float*      src = (w < N_ROWS) ? (x + (size_t)w * K_DIM) : (y + (size_t)(w - N_ROWS) * K_DIM);
    __hip_bfloat16*   dst = (w < N_ROWS) ? (xb + (size_t)w * K_DIM) : (yb + (size_t)(w - N_ROWS) * K_DIM);
    float s = 0.f;
    #pragma unroll
    for (int i = 0; i < 3; ++i) {                // 192 = 3 * 64
        float f = src[lane + 64 * i];
        __hip_bfloat16 h = __float2bfloat16(f);
        dst[lane + 64 * i] = h;
        float fb = __bfloat162float(h);
        s += fb * fb;
    }
    #pragma unroll
    for (int off = 32; off; off >>= 1) s += __shfl_down(s, off, 64);
    if (lane == 0) {
        if (w < N_ROWS) sqx[w] = s; else sqy[w - N_ROWS] = s;
    }
}

// ---- kernel 2: fused Gram + exp + block reduce ----
// 256 thr / 4 waves, 128x128 tile, K=192 as two 96-wide stages in SEPARATE LDS
// regions via global_load_lds (no staging VGPRs, no spill). LDS rows = 12
// 16B-chunks (192B, no pad); k-chunk positions XOR-swizzled per row so the
// MFMA fragment ds_read_b128s are bank-conflict-free:
//   slot jp<8  holds global chunk jp ^ (row&7)
//   slot jp>=8 holds global chunk 8 + ((jp + ((row>>1)&3)) & 3)
extern __shared__ char smem[];

__global__ __launch_bounds__(256)
void gram_kernel(const __hip_bfloat16* __restrict__ xb, const __hip_bfloat16* __restrict__ yb,
                 const float* __restrict__ sqx, const float* __restrict__ sqy,
                 float* __restrict__ partials)
{
    const short* xbs = (const short*)xb;
    const short* ybs = (const short*)yb;

    int id = blockIdx.x;
    const short *A, *B; const float *sa, *sb;
    int bi, bj;
    float weight = 1.0f;
    if (id < 2 * NSYM) {
        int t;
        if (id < NSYM) { t = id;        A = xbs; B = xbs; sa = sqx; sb = sqx; }
        else           { t = id - NSYM; A = ybs; B = ybs; sa = sqy; sb = sqy; }
        bi = 0;
        while (t >= NT - bi) { t -= NT - bi; ++bi; }   // unrank upper triangle
        bj = bi + t;
        if (bi != bj) weight = 2.0f;                   // symmetry: off-diag counts twice
    } else {
        int t = id - 2 * NSYM;
        bi = t >> 5; bj = t & 31;
        A = xbs; B = ybs; sa = sqx; sb = sqy;
    }
    const int abase = bi * 128, bbase = bj * 128;

    const int tid  = threadIdx.x;
    const int lane = tid & 63, w = tid >> 6;
    const int wm   = w >> 1,  wn = w & 1;
    const int m15  = lane & 15, quad = lane >> 4;

    // ---- per-lane swizzled global byte offsets for staging (6 chunks/thread/panel) ----
    int offG[6];
    #pragma unroll
    for (int i = 0; i < 6; ++i) {
        int c  = i * 256 + tid;            // LDS chunk slot 0..1535
        int r  = (c * 683) >> 13;          // c / 12 (exact for c < 2048)
        int jp = c - 12 * r;               // slot within row, 0..11
        int js = (jp < 8) ? (jp ^ (r & 7)) : (8 + ((jp + ((r >> 1) & 3)) & 3));
        offG[i] = r * 384 + js * 16;       // bytes within 128-row panel (row = 384B)
    }
    const char* ApanB = (const char*)(A + (size_t)abase * K_DIM);
    const char* BpanB = (const char*)(B + (size_t)bbase * K_DIM);

    // ---- issue stage-0 DMA (k-chunks 0..11) ----
    #pragma unroll
    for (int i = 0; i < 6; ++i) {
        int d = (i * 256 + w * 64) * 16;   // wave-uniform LDS byte base
        gload16(ApanB + offG[i],       smem + REG_A0 + d);
        gload16(BpanB + offG[i],       smem + REG_B0 + d);
    }

    // ---- fragment LDS read offsets (region-relative), swizzle-aware ----
    int adA[3][4], adB[3][4];
    #pragma unroll
    for (int tm = 0; tm < 4; ++tm) {
        int rA = wm * 64 + tm * 16 + m15;
        int kA = rA & 7, mA = (rA >> 1) & 3, rbA = rA * 192;
        int rB = wn * 64 + tm * 16 + m15;
        int kB = rB & 7, mB = (rB >> 1) & 3, rbB = rB * 192;
        adA[0][tm] = rbA + ((quad)      ^ kA) * 16;                 // j = quad
        adA[1][tm] = rbA + ((4 + quad)  ^ kA) * 16;                 // j = 4+quad
        adA[2][tm] = rbA + (8 + ((quad + 4 - mA) & 3)) * 16;        // j = 8+quad
        adB[0][tm] = rbB + ((quad)      ^ kB) * 16;
        adB[1][tm] = rbB + ((4 + quad)  ^ kB) * 16;
        adB[2][tm] = rbB + (8 + ((quad + 4 - mB) & 3)) * 16;
    }

    // ---- sq terms (scaled by C1) ----
    float4v ua[4]; float vb4[4];
    #pragma unroll
    for (int tm = 0; tm < 4; ++tm)
        ua[tm] = (*(const float4v*)&sa[abase + wm * 64 + tm * 16 + quad * 4]) * C1;
    #pragma unroll
    for (int tn = 0; tn < 4; ++tn)
        vb4[tn] = C1 * sb[bbase + wn * 64 + tn * 16 + m15];

    float4v acc[4][4];
    #pragma unroll
    for (int i = 0; i < 4; ++i)
        #pragma unroll
        for (int j = 0; j < 4; ++j) acc[i][j] = (float4v){0.f, 0.f, 0.f, 0.f};

    __syncthreads();   // stage-0 DMA drained (vmcnt0 + barrier)

    // ---- issue stage-1 DMA now (k-chunks 12..23, +192B) — hides under stage-0 compute ----
    #pragma unroll
    for (int i = 0; i < 6; ++i) {
        int d = (i * 256 + w * 64) * 16;
        gload16(ApanB + offG[i] + 192, smem + REG_S1 + d);
        gload16(BpanB + offG[i] + 192, smem + REG_S1 + 24576 + d);
    }

    // ---- stage-0 compute ----
    #pragma unroll
    for (int t = 0; t < 3; ++t) {
        short8 af[4], bfr[4];
        #pragma unroll
        for (int tm = 0; tm < 4; ++tm) af[tm]  = *(const short8*)(smem + REG_A0 + adA[t][tm]);
        #pragma unroll
        for (int tn = 0; tn < 4; ++tn) bfr[tn] = *(const short8*)(smem + REG_B0 + adB[t][tn]);
        #pragma unroll
        for (int tm = 0; tm < 4; ++tm)
            #pragma unroll
            for (int tn = 0; tn < 4; ++tn)
                acc[tm][tn] = __builtin_amdgcn_mfma_f32_16x16x32_bf16(af[tm], bfr[tn], acc[tm][tn], 0, 0, 0);
    }

    __syncthreads();   // stage-1 DMA drained (latency covered by stage-0 compute)

    // ---- stage-1 compute ----
    #pragma unroll
    for (int t = 0; t < 3; ++t) {
        short8 af[4], bfr[4];
        #pragma unroll
        for (int tm = 0; tm < 4; ++tm) af[tm]  = *(const short8*)(smem + REG_S1 + adA[t][tm]);
        #pragma unroll
        for (int tn = 0; tn < 4; ++tn) bfr[tn] = *(const short8*)(smem + REG_S1 + 24576 + adB[t][tn]);
        #pragma unroll
        for (int tm = 0; tm < 4; ++tm)
            #pragma unroll
            for (int tn = 0; tn < 4; ++tn)
                acc[tm][tn] = __builtin_amdgcn_mfma_f32_16x16x32_bf16(af[tm], bfr[tn], acc[tm][tn], 0, 0, 0);
    }

    // ---- epilogue: sum exp2(min(C1*sqa + C1*sqb + log2e*g, 0)), skip underflow tiles ----
    float lsum = 0.f;
    #pragma unroll
    for (int tm = 0; tm < 4; ++tm)
        #pragma unroll
        for (int tn = 0; tn < 4; ++tn) {
            float vv = vb4[tn];
            float s0 = fminf(ua[tm][0] + vv + LOG2E * acc[tm][tn][0], 0.f);
            float s1 = fminf(ua[tm][1] + vv + LOG2E * acc[tm][tn][1], 0.f);
            float s2 = fminf(ua[tm][2] + vv + LOG2E * acc[tm][tn][2], 0.f);
            float s3 = fminf(ua[tm][3] + vv + LOG2E * acc[tm][tn][3], 0.f);
            float mx = fmaxf(fmaxf(s0, s1), fmaxf(s2, s3));
            if (__ballot(mx > -40.f)) {   // whole 16x16 tile underflows -> skip (execz)
                lsum += __builtin_amdgcn_exp2f(s0) + __builtin_amdgcn_exp2f(s1)
                      + __builtin_amdgcn_exp2f(s2) + __builtin_amdgcn_exp2f(s3);
            }
        }

    #pragma unroll
    for (int off = 32; off; off >>= 1) lsum += __shfl_down(lsum, off, 64);
    float* wred = (float*)(smem + 98304);
    if (lane == 0) wred[w] = lsum;
    __syncthreads();
    if (tid == 0)
        partials[id] = weight * (wred[0] + wred[1] + wred[2] + wred[3]);
}

// ---- kernel 3: final reduce + loss ----
__global__ void final_kernel(const float* __restrict__ partials, const float* __restrict__ avg_step,
                             float* __restrict__ out)
{
    __shared__ float red[3][4];
    int tid = threadIdx.x, lane = tid & 63, w = tid >> 6;
    float s0 = 0.f, s1 = 0.f, s2 = 0.f;
    for (int i = tid; i < NSYM; i += 256) s0 += partials[i];
    for (int i = tid; i < NSYM; i += 256) s1 += partials[NSYM + i];
    for (int i = tid; i < 1024; i += 256) s2 += partials[2 * NSYM + i];
    #pragma unroll
    for (int off = 32; off; off >>= 1) {
        s0 += __shfl_down(s0, off, 64);
        s1 += __shfl_down(s1, off, 64);
        s2 += __shfl_down(s2, off, 64);
    }
    if (lane == 0) { red[0][w] = s0; red[1][w] = s1; red[2][w] = s2; }
    __syncthreads();
    if (tid == 0) {
        float sxx = red[0][0] + red[0][1] + red[0][2] + red[0][3];
        float syy = red[1][0] + red[1][1] + red[1][2] + red[1][3];
        float sxy = red[2][0] + red[2][1] + red[2][2] + red[2][3];
        const float inv = 1.0f / 16777216.0f;   // 1/4096^2
        float mmd   = (sxx + syy - 2.0f * sxy) * inv;
        float stepv = fmaxf(1.0f, avg_step[0]);
        out[0] = mmd + (stepv - 1.0f) * 0.002f;
        out[1] = mmd;
    }
}

extern "C" void kernel_launch(void* const* d_in, const int* in_sizes, int n_in,
                              void* d_out, int out_size, void* d_ws, size_t ws_size,
                              hipStream_t stream)
{
    const float* x        = (const float*)d_in[0];
    const float* y        = (const float*)d_in[1];
    const float* avg_step = (const float*)d_in[2];

    char* ws = (char*)d_ws;
    __hip_bfloat16* xb       = (__hip_bfloat16*)(ws);
    __hip_bfloat16* yb       = (__hip_bfloat16*)(ws + 1572864);
    float*          sqx      = (float*)(ws + 3145728);
    float*          sqy      = (float*)(ws + 3162112);
    float*          partials = (float*)(ws + 3178496);

    hipFuncSetAttribute(reinterpret_cast<const void*>(gram_kernel),
                        hipFuncAttributeMaxDynamicSharedMemorySize, LDS_TOTAL);

    prep_kernel<<<2048, 256, 0, stream>>>(x, y, xb, yb, sqx, sqy);
    gram_kernel<<<NBLK, 256, LDS_TOTAL, stream>>>(xb, yb, sqx, sqy, partials);
    final_kernel<<<1, 256, 0, stream>>>(partials, avg_step, (float*)d_out);
}